// Round 3
// baseline (325.790 us; speedup 1.0000x reference)
//
#include <hip/hip_runtime.h>
#include <hip/hip_bf16.h>
#include <math.h>

#define FREQS 9
#define DATA_DIM 28
#define WIDTH 128
#define IN_DIM 82
#define KPAD 96
#define W1STRIDE 104   // shorts per LDS row (208 B) -> ~2-way bank conflicts

typedef float f32x4 __attribute__((ext_vector_type(4)));
typedef short s16x8 __attribute__((ext_vector_type(8)));

__device__ __forceinline__ short f2bf(float f) {
    unsigned u = __builtin_bit_cast(unsigned, f);
    u += 0x7fffu + ((u >> 16) & 1u);
    return (short)(u >> 16);
}

// ws: [0] nz counter, [1] mask-width flag, [64..64+B) counts, [64+B..64+2B) offsets,
// then W1bf (128*96 bf16, b1 folded at k=82)

__global__ void k_zero(int* ws) { ws[0] = 0; }

__global__ void k_count_bytes(const unsigned int* __restrict__ mw, int nwords, int* ws) {
    int tid = blockIdx.x * blockDim.x + threadIdx.x;
    int stride = gridDim.x * blockDim.x;
    int c = 0;
    for (int i = tid; i < nwords; i += stride) {
        unsigned int w = mw[i];
        c += ((w & 0xffu) != 0) + (((w >> 8) & 0xffu) != 0) +
             (((w >> 16) & 0xffu) != 0) + ((w >> 24) != 0);
    }
    __shared__ int red[256];
    red[threadIdx.x] = c;
    __syncthreads();
    for (int off = 128; off > 0; off >>= 1) {
        if (threadIdx.x < off) red[threadIdx.x] += red[threadIdx.x + off];
        __syncthreads();
    }
    if (threadIdx.x == 0) atomicAdd(&ws[0], red[0]);
}

__global__ void k_set_flag(int* ws, int P) { ws[1] = (ws[0] == P) ? 1 : 0; }

__global__ void k_ray_count(const void* __restrict__ maskp, const int* __restrict__ wsflag,
                            int* __restrict__ cnt, int N) {
    int b = blockIdx.x;
    int lane = threadIdx.x;
    int fl = wsflag[0];
    const unsigned char* m8 = (const unsigned char*)maskp;
    const int* m32 = (const int*)maskp;
    int base = 0;
    for (int t = 0; t < N / 64; ++t) {
        int n = t * 64 + lane;
        int mv = fl ? (int)m8[(size_t)b * N + n] : m32[(size_t)b * N + n];
        unsigned long long bal = __ballot(mv != 0);
        base += __popcll(bal);
    }
    if (lane == 0) cnt[b] = base;
}

__global__ void k_scan(const int* __restrict__ cnt, int* __restrict__ roff, int Bn) {
    __shared__ int sums[1024];
    int tid = threadIdx.x;
    int per = Bn / 1024;
    int loc[8];
    int s = 0;
    for (int i = 0; i < per; ++i) { loc[i] = s; s += cnt[tid * per + i]; }
    sums[tid] = s;
    __syncthreads();
    for (int off = 1; off < 1024; off <<= 1) {
        int t = sums[tid];
        int v = (tid >= off) ? sums[tid - off] : 0;
        __syncthreads();
        sums[tid] = t + v;
        __syncthreads();
    }
    int excl = sums[tid] - s;
    for (int i = 0; i < per; ++i) roff[tid * per + i] = excl + loc[i];
}

__global__ void k_prep(const float* __restrict__ W1, const float* __restrict__ b1,
                       short* __restrict__ W1bf) {
    int tid = blockIdx.x * blockDim.x + threadIdx.x;
    if (tid < WIDTH * KPAD) {
        int n = tid / KPAD, k = tid - n * KPAD;
        float v = (k < IN_DIM) ? W1[n * IN_DIM + k] : ((k == IN_DIM) ? b1[n] : 0.0f);
        W1bf[tid] = f2bf(v);
    }
}

// 256 threads = 4 waves = 4 rays per block
__global__ __launch_bounds__(256, 3) void k_render(
    const float* __restrict__ rays_d, const float* __restrict__ intrs,
    const void* __restrict__ maskp, const float* __restrict__ data,
    const short* __restrict__ W1bf, const float* __restrict__ W2,
    const float* __restrict__ b2,
    const int* __restrict__ wsflag, const int* __restrict__ roff,
    float* __restrict__ out, int Bn, int N, int P)
{
    int wid = threadIdx.x >> 6;
    int lane = threadIdx.x & 63;
    int b = blockIdx.x * 4 + wid;
    int g = lane >> 4, c = lane & 15;

    float* out_comp = out;
    float* out_alpha = out + (size_t)Bn * 3;

    __shared__ int nlist[4][256];
    __shared__ __align__(16) float w2s[WIDTH * 4];
    __shared__ __align__(16) short w1s[WIDTH * W1STRIDE];

    // Stage W2^T (128x4 f32) and W1bf (rows padded to 104 shorts) into LDS.
    for (int idx = threadIdx.x; idx < WIDTH * 4; idx += 256) {
        int j = idx >> 2, o = idx & 3;
        w2s[idx] = W2[o * WIDTH + j];
    }
    {
        const f32x4* src = reinterpret_cast<const f32x4*>(W1bf);
        for (int t = threadIdx.x; t < WIDTH * 12; t += 256) {
            int row = t / 12, seg = t - row * 12;
            *reinterpret_cast<f32x4*>(&w1s[row * W1STRIDE + seg * 8]) = src[t];
        }
    }

    int fl = wsflag[0];
    const unsigned char* m8 = (const unsigned char*)maskp;
    const int* m32 = (const int*)maskp;

    // Masked-n list per wave; zero alpha for unmasked.
    int base = 0;
    for (int t = 0; t < N / 64; ++t) {
        int n = t * 64 + lane;
        int mv = fl ? (int)m8[(size_t)b * N + n] : m32[(size_t)b * N + n];
        bool m = (mv != 0);
        unsigned long long bal = __ballot(m);
        int rank = __popcll(bal & ((1ull << lane) - 1ull));
        if (m) nlist[wid][base + rank] = n;
        else   out_alpha[(size_t)b * N + n] = 0.0f;
        base += __popcll(bal);
    }
    __syncthreads();
    int count = base;
    int poff = roff[b];

    float dx = rays_d[b * 3 + 0], dy = rays_d[b * 3 + 1], dz = rays_d[b * 3 + 2];
    float nrm = sqrtf(dx * dx + dy * dy + dz * dz);

    // PE lane-parallel: pe[f*6+t], t<3: sin(d[t]*2^f), else cos.
    int idx = (lane < 54) ? lane : 0;
    int fb = idx / 6, t5 = idx - fb * 6;
    int ax = (t5 < 3) ? t5 : (t5 - 3);
    float dv = (ax == 0) ? dx : ((ax == 1) ? dy : dz);
    float ang = dv * (float)(1 << fb);
    float pev = (t5 < 3) ? sinf(ang) : cosf(ang);

    // X fragments for K-steps 1,2 (per-ray constant). k=82 -> 1.0 (bias column).
    s16x8 aPE1, aPE2;
    short peT[4];
    #pragma unroll
    for (int j = 0; j < 8; ++j) {
        int i1 = 4 + 8 * g + j;
        aPE1[j] = f2bf(__shfl(pev, i1, 64));
        int i2 = 36 + 8 * g + j;
        float v2 = __shfl(pev, (i2 < 54) ? i2 : 0, 64);
        float vv = (i2 < 54) ? v2 : ((i2 == 54) ? 1.0f : 0.0f);
        aPE2[j] = f2bf(vv);
    }
    #pragma unroll
    for (int j = 0; j < 4; ++j) peT[j] = f2bf(__shfl(pev, j, 64));  // k=28..31

    f32x4 b2v = *reinterpret_cast<const f32x4*>(b2);

    float T = 1.0f;
    float aR = 0.f, aG = 0.f, aB = 0.f, aA = 0.f;

    f32x4 rawLo[4], rawHi[4];
    auto issue = [&](int r0n) {
        #pragma unroll
        for (int mb = 0; mb < 4; ++mb) {
            int srow = poff + r0n + 16 * mb + c;
            srow = (srow < P) ? srow : (P - 1);
            const float* dr = data + (size_t)srow * DATA_DIM;
            rawLo[mb] = *reinterpret_cast<const f32x4*>(dr + 8 * g);
            const float* hp = (g < 3) ? (dr + 8 * g + 4) : dr;   // g==3: dummy (peT used)
            rawHi[mb] = *reinterpret_cast<const f32x4*>(hp);
        }
    };
    issue(0);

    for (int r0 = 0; r0 < count; r0 += 64) {
        int r = r0 + lane;
        bool act = (r < count);
        int n = act ? nlist[wid][r] : 0;

        // Build X B-fragments for K-step 0 from prefetched rows.
        s16x8 a0[4];
        #pragma unroll
        for (int mb = 0; mb < 4; ++mb) {
            #pragma unroll
            for (int j = 0; j < 4; ++j) a0[mb][j] = f2bf(rawLo[mb][j]);
            #pragma unroll
            for (int j = 0; j < 4; ++j) {
                short hv = f2bf(rawHi[mb][j]);
                a0[mb][4 + j] = (g < 3) ? hv : peT[j];
            }
        }
        if (r0 + 64 < count) issue(r0 + 64);   // prefetch next batch

        f32x4 acc[4];
        #pragma unroll
        for (int mb = 0; mb < 4; ++mb) acc[mb] = (f32x4){0.f, 0.f, 0.f, 0.f};

        #pragma unroll
        for (int nt = 0; nt < 8; ++nt) {
            const short* wr = &w1s[(16 * nt + c) * W1STRIDE];
            s16x8 Bk0 = *reinterpret_cast<const s16x8*>(wr + g * 8);
            s16x8 Bk1 = *reinterpret_cast<const s16x8*>(wr + 32 + g * 8);
            s16x8 Bk2 = *reinterpret_cast<const s16x8*>(wr + 64 + g * 8);

            // Swapped: D = W1 x X^T -> H^T tile (rows=neurons 16nt+4g+q, cols=samples 16mb+c)
            f32x4 C0 = {0.f,0.f,0.f,0.f}, C1 = C0, C2 = C0, C3 = C0;
            C0 = __builtin_amdgcn_mfma_f32_16x16x32_bf16(Bk0, a0[0], C0, 0, 0, 0);
            C1 = __builtin_amdgcn_mfma_f32_16x16x32_bf16(Bk0, a0[1], C1, 0, 0, 0);
            C2 = __builtin_amdgcn_mfma_f32_16x16x32_bf16(Bk0, a0[2], C2, 0, 0, 0);
            C3 = __builtin_amdgcn_mfma_f32_16x16x32_bf16(Bk0, a0[3], C3, 0, 0, 0);
            C0 = __builtin_amdgcn_mfma_f32_16x16x32_bf16(Bk1, aPE1, C0, 0, 0, 0);
            C1 = __builtin_amdgcn_mfma_f32_16x16x32_bf16(Bk1, aPE1, C1, 0, 0, 0);
            C2 = __builtin_amdgcn_mfma_f32_16x16x32_bf16(Bk1, aPE1, C2, 0, 0, 0);
            C3 = __builtin_amdgcn_mfma_f32_16x16x32_bf16(Bk1, aPE1, C3, 0, 0, 0);
            C0 = __builtin_amdgcn_mfma_f32_16x16x32_bf16(Bk2, aPE2, C0, 0, 0, 0);
            C1 = __builtin_amdgcn_mfma_f32_16x16x32_bf16(Bk2, aPE2, C1, 0, 0, 0);
            C2 = __builtin_amdgcn_mfma_f32_16x16x32_bf16(Bk2, aPE2, C2, 0, 0, 0);
            C3 = __builtin_amdgcn_mfma_f32_16x16x32_bf16(Bk2, aPE2, C3, 0, 0, 0);

            // Layer 2 partials: lane's neurons are 16nt+4g+q; sample = 16mb+c.
            #pragma unroll
            for (int q = 0; q < 4; ++q) {
                f32x4 w2r = *reinterpret_cast<const f32x4*>(&w2s[(16 * nt + 4 * g + q) * 4]);
                float h0 = fmaxf(C0[q], 0.f);
                float h1 = fmaxf(C1[q], 0.f);
                float h2 = fmaxf(C2[q], 0.f);
                float h3 = fmaxf(C3[q], 0.f);
                acc[0] += w2r * h0;
                acc[1] += w2r * h1;
                acc[2] += w2r * h2;
                acc[3] += w2r * h3;
            }
        }

        // Reduce partials over g (neurons split across g), then pick mb == own g.
        #pragma unroll
        for (int mb = 0; mb < 4; ++mb)
            #pragma unroll
            for (int comp = 0; comp < 4; ++comp) {
                float v = acc[mb][comp];
                v += __shfl_xor(v, 16, 64);
                v += __shfl_xor(v, 32, 64);
                acc[mb][comp] = v;
            }
        f32x4 pre  = (g & 1) ? acc[1] : acc[0];
        f32x4 preB = (g & 1) ? acc[3] : acc[2];
        pre = (g & 2) ? preB : pre;       // sample 16g+c == lane
        pre += b2v;

        float p0 = pre[0], p1 = pre[1], p2 = pre[2], p3 = pre[3];

        float density = fmaxf(p0, 0.0f);
        float dist = (intrs[(size_t)b * (N + 1) + n + 1] - intrs[(size_t)b * (N + 1) + n]) * nrm;
        float alpha = act ? (1.0f - expf(-density * dist)) : 0.0f;

        float fct = 1.0f - alpha + 1e-10f;
        float scan = fct;
        #pragma unroll
        for (int d = 1; d < 64; d <<= 1) {
            float o = __shfl_up(scan, d, 64);
            if (lane >= d) scan *= o;
        }
        float tot  = __shfl(scan, 63, 64);
        float excl = __shfl_up(scan, 1, 64);
        if (lane == 0) excl = 1.0f;

        float cum  = T * excl;
        float absl = alpha * cum;
        float sR = 1.0f / (1.0f + expf(-p1));
        float sG = 1.0f / (1.0f + expf(-p2));
        float sB = 1.0f / (1.0f + expf(-p3));
        aR = fmaf(absl, sR, aR);
        aG = fmaf(absl, sG, aG);
        aB = fmaf(absl, sB, aB);
        aA += absl;
        T *= tot;

        if (act) out_alpha[(size_t)b * N + n] = alpha;
    }

    #pragma unroll
    for (int d = 32; d > 0; d >>= 1) {
        aR += __shfl_down(aR, d, 64);
        aG += __shfl_down(aG, d, 64);
        aB += __shfl_down(aB, d, 64);
        aA += __shfl_down(aA, d, 64);
    }
    if (lane == 0) {
        out_comp[b * 3 + 0] = aR + (1.0f - aA);
        out_comp[b * 3 + 1] = aG + (1.0f - aA);
        out_comp[b * 3 + 2] = aB + (1.0f - aA);
    }
}

extern "C" void kernel_launch(void* const* d_in, const int* in_sizes, int n_in,
                              void* d_out, int out_size, void* d_ws, size_t ws_size,
                              hipStream_t stream) {
    const float* rays_d = (const float*)d_in[0];
    const float* intrs  = (const float*)d_in[1];
    const void*  maskp  = d_in[2];
    const float* data   = (const float*)d_in[3];
    const float* W1     = (const float*)d_in[4];
    const float* b1     = (const float*)d_in[5];
    const float* W2     = (const float*)d_in[6];
    const float* b2     = (const float*)d_in[7];
    float* out = (float*)d_out;

    int B = in_sizes[0] / 3;            // 8192
    int N = in_sizes[2] / B;            // 256
    int P = in_sizes[3] / DATA_DIM;     // packed sample count

    int* wsI    = (int*)d_ws;
    int* cnt    = wsI + 64;
    int* roff   = wsI + 64 + B;
    short* W1bf = (short*)(wsI + 64 + 2 * B);

    k_zero<<<1, 1, 0, stream>>>(wsI);
    int nwords = (B * N) / 4;
    k_count_bytes<<<256, 256, 0, stream>>>((const unsigned int*)maskp, nwords, wsI);
    k_set_flag<<<1, 1, 0, stream>>>(wsI, P);
    k_ray_count<<<B, 64, 0, stream>>>(maskp, wsI + 1, cnt, N);
    k_scan<<<1, 1024, 0, stream>>>(cnt, roff, B);
    k_prep<<<(WIDTH * KPAD + 255) / 256, 256, 0, stream>>>(W1, b1, W1bf);
    k_render<<<B / 4, 256, 0, stream>>>(rays_d, intrs, maskp, data, W1bf, W2, b2,
                                        wsI + 1, roff, out, B, N, P);
}

// Round 5
// 160.862 us; speedup vs baseline: 2.0253x; 2.0253x over previous
//
#include <hip/hip_runtime.h>
#include <hip/hip_bf16.h>
#include <math.h>

#define FREQS 9
#define DATA_DIM 28
#define WIDTH 128
#define IN_DIM 82
#define KPAD 96
#define HSTRIDE 40   // shorts per sample row in H stripe (80 B) -> ~2-way conflicts

typedef float f32x4 __attribute__((ext_vector_type(4)));
typedef short s16x8 __attribute__((ext_vector_type(8)));

__device__ __forceinline__ short f2bf(float f) {
    unsigned u = __builtin_bit_cast(unsigned, f);
    u += 0x7fffu + ((u >> 16) & 1u);
    return (short)(u >> 16);
}

__device__ __forceinline__ unsigned pk2(float a, float b) {
    unsigned lo = (unsigned)(unsigned short)f2bf(a);
    unsigned hi = (unsigned)(unsigned short)f2bf(b);
    return lo | (hi << 16);
}

// ws: [0] nz counter, [1] mask-width flag, [64..64+B) counts, [64+B..64+2B) offsets,
// then W1bf (128*96 bf16, b1 folded at k=82)

__global__ void k_zero(int* ws) { ws[0] = 0; }

__global__ void k_count_bytes(const unsigned int* __restrict__ mw, int nwords, int* ws) {
    int tid = blockIdx.x * blockDim.x + threadIdx.x;
    int stride = gridDim.x * blockDim.x;
    int c = 0;
    for (int i = tid; i < nwords; i += stride) {
        unsigned int w = mw[i];
        c += ((w & 0xffu) != 0) + (((w >> 8) & 0xffu) != 0) +
             (((w >> 16) & 0xffu) != 0) + ((w >> 24) != 0);
    }
    __shared__ int red[256];
    red[threadIdx.x] = c;
    __syncthreads();
    for (int off = 128; off > 0; off >>= 1) {
        if (threadIdx.x < off) red[threadIdx.x] += red[threadIdx.x + off];
        __syncthreads();
    }
    if (threadIdx.x == 0) atomicAdd(&ws[0], red[0]);
}

__global__ void k_set_flag(int* ws, int P) { ws[1] = (ws[0] == P) ? 1 : 0; }

__global__ void k_ray_count(const void* __restrict__ maskp, const int* __restrict__ wsflag,
                            int* __restrict__ cnt, int N) {
    int b = blockIdx.x;
    int lane = threadIdx.x;
    int fl = wsflag[0];
    const unsigned char* m8 = (const unsigned char*)maskp;
    const int* m32 = (const int*)maskp;
    int base = 0;
    for (int t = 0; t < N / 64; ++t) {
        int n = t * 64 + lane;
        int mv = fl ? (int)m8[(size_t)b * N + n] : m32[(size_t)b * N + n];
        unsigned long long bal = __ballot(mv != 0);
        base += __popcll(bal);
    }
    if (lane == 0) cnt[b] = base;
}

__global__ void k_scan(const int* __restrict__ cnt, int* __restrict__ roff, int Bn) {
    __shared__ int sums[1024];
    int tid = threadIdx.x;
    int per = Bn / 1024;
    int loc[8];
    int s = 0;
    for (int i = 0; i < per; ++i) { loc[i] = s; s += cnt[tid * per + i]; }
    sums[tid] = s;
    __syncthreads();
    for (int off = 1; off < 1024; off <<= 1) {
        int t = sums[tid];
        int v = (tid >= off) ? sums[tid - off] : 0;
        __syncthreads();
        sums[tid] = t + v;
        __syncthreads();
    }
    int excl = sums[tid] - s;
    for (int i = 0; i < per; ++i) roff[tid * per + i] = excl + loc[i];
}

__global__ void k_prep(const float* __restrict__ W1, const float* __restrict__ b1,
                       short* __restrict__ W1bf) {
    int tid = blockIdx.x * blockDim.x + threadIdx.x;
    if (tid < WIDTH * KPAD) {
        int n = tid / KPAD, k = tid - n * KPAD;
        float v = (k < IN_DIM) ? W1[n * IN_DIM + k] : ((k == IN_DIM) ? b1[n] : 0.0f);
        W1bf[tid] = f2bf(v);
    }
}

// 256 threads = 4 waves = 4 rays per block; waves fully independent (no barriers).
__global__ __launch_bounds__(256, 3) void k_render(
    const float* __restrict__ rays_d, const float* __restrict__ intrs,
    const void* __restrict__ maskp, const float* __restrict__ data,
    const short* __restrict__ W1bf, const float* __restrict__ W2,
    const float* __restrict__ b2,
    const int* __restrict__ wsflag, const int* __restrict__ roff,
    float* __restrict__ out, int Bn, int N, int P)
{
    int wid = threadIdx.x >> 6;
    int lane = threadIdx.x & 63;
    int b = blockIdx.x * 4 + wid;
    int g = lane >> 4, c = lane & 15;

    float* out_comp = out;
    float* out_alpha = out + (size_t)Bn * 3;

    __shared__ int nlist[4][256];
    __shared__ __align__(16) short hbuf[4][64 * HSTRIDE];   // 20 KB
    __shared__ __align__(16) float ppre[4][64][4];          // 4 KB

    int fl = wsflag[0];
    const unsigned char* m8 = (const unsigned char*)maskp;
    const int* m32 = (const int*)maskp;

    // Phase 1: per-wave masked-n list; zero alpha for unmasked.
    int base = 0;
    for (int t = 0; t < N / 64; ++t) {
        int n = t * 64 + lane;
        int mv = fl ? (int)m8[(size_t)b * N + n] : m32[(size_t)b * N + n];
        bool m = (mv != 0);
        unsigned long long bal = __ballot(m);
        int rank = __popcll(bal & ((1ull << lane) - 1ull));
        if (m) nlist[wid][base + rank] = n;
        else   out_alpha[(size_t)b * N + n] = 0.0f;
        base += __popcll(bal);
    }
    int count = base;
    int poff = roff[b];

    float dx = rays_d[b * 3 + 0], dy = rays_d[b * 3 + 1], dz = rays_d[b * 3 + 2];
    float nrm = sqrtf(dx * dx + dy * dy + dz * dz);

    // PE lane-parallel: pe[f*6+t], t<3: sin(d[t]*2^f), else cos.
    int idx = (lane < 54) ? lane : 0;
    int fb = idx / 6, t5 = idx - fb * 6;
    int ax = (t5 < 3) ? t5 : (t5 - 3);
    float dv = (ax == 0) ? dx : ((ax == 1) ? dy : dz);
    float ang = dv * (float)(1 << fb);
    float pev = (t5 < 3) ? sinf(ang) : cosf(ang);

    // X fragments for K-steps 1,2 (per-ray constant). k=82 -> 1.0 (bias column).
    s16x8 aPE1, aPE2;
    #pragma unroll
    for (int j = 0; j < 8; ++j) {
        int i1 = 4 + 8 * g + j;
        aPE1[j] = f2bf(__shfl(pev, i1, 64));
        int i2 = 36 + 8 * g + j;
        float v2 = __shfl(pev, (i2 < 54) ? i2 : 0, 64);
        float vv = (i2 < 54) ? v2 : ((i2 == 54) ? 1.0f : 0.0f);
        aPE2[j] = f2bf(vv);
    }
    unsigned peTx = pk2(__shfl(pev, 0, 64), __shfl(pev, 1, 64));   // k=28,29
    unsigned peTy = pk2(__shfl(pev, 2, 64), __shfl(pev, 3, 64));   // k=30,31

    // W2 A-fragments (per-lane constant): A[row=c][k=32ks+8g+j], rows>=4 zero.
    s16x8 w2f[4];
    #pragma unroll
    for (int ks = 0; ks < 4; ++ks) {
        if (c < 4) {
            const float* wp = W2 + c * WIDTH + 32 * ks + 8 * g;
            f32x4 u = *reinterpret_cast<const f32x4*>(wp);
            f32x4 v = *reinterpret_cast<const f32x4*>(wp + 4);
            #pragma unroll
            for (int j = 0; j < 4; ++j) {
                w2f[ks][j] = f2bf(u[j]);
                w2f[ks][4 + j] = f2bf(v[j]);
            }
        } else {
            #pragma unroll
            for (int j = 0; j < 8; ++j) w2f[ks][j] = 0;
        }
    }

    f32x4 b2v = *reinterpret_cast<const f32x4*>(b2);
    const s16x8* W1v = reinterpret_cast<const s16x8*>(W1bf);
    short* hb = &hbuf[wid][0];

    float T = 1.0f;
    float aR = 0.f, aG = 0.f, aB = 0.f, aA = 0.f;

    for (int r0 = 0; r0 < count; r0 += 64) {
        int r = r0 + lane;
        bool act = (r < count);
        int n = act ? nlist[wid][r] : 0;

        // X B-fragments, K-step 0: data cols (g=3: 24..27 + pe tail)
        s16x8 a0[4];
        #pragma unroll
        for (int mb = 0; mb < 4; ++mb) {
            int srow = poff + r0 + 16 * mb + c;
            srow = (srow < P) ? srow : (P - 1);
            const float* dr = data + (size_t)srow * DATA_DIM;
            f32x4 lo = *reinterpret_cast<const f32x4*>(dr + 8 * g);
            unsigned u0 = pk2(lo[0], lo[1]);
            unsigned u1 = pk2(lo[2], lo[3]);
            unsigned u2, u3;
            if (g < 3) {
                f32x4 hi = *reinterpret_cast<const f32x4*>(dr + 8 * g + 4);
                u2 = pk2(hi[0], hi[1]);
                u3 = pk2(hi[2], hi[3]);
            } else {
                u2 = peTx; u3 = peTy;
            }
            uint4 uu; uu.x = u0; uu.y = u1; uu.z = u2; uu.w = u3;
            a0[mb] = __builtin_bit_cast(s16x8, uu);
        }

        f32x4 D[4];
        #pragma unroll
        for (int t = 0; t < 4; ++t) D[t] = (f32x4){0.f, 0.f, 0.f, 0.f};

        #pragma unroll
        for (int ks = 0; ks < 4; ++ks) {
            #pragma unroll
            for (int h = 0; h < 2; ++h) {
                int nt = 2 * ks + h;
                int nrow = 16 * nt + c;
                s16x8 Bk0 = W1v[nrow * 12 + g];
                s16x8 Bk1 = W1v[nrow * 12 + 4 + g];
                s16x8 Bk2 = W1v[nrow * 12 + 8 + g];

                f32x4 C0 = {0.f,0.f,0.f,0.f}, C1 = C0, C2 = C0, C3 = C0;
                C0 = __builtin_amdgcn_mfma_f32_16x16x32_bf16(Bk0, a0[0], C0, 0, 0, 0);
                C1 = __builtin_amdgcn_mfma_f32_16x16x32_bf16(Bk0, a0[1], C1, 0, 0, 0);
                C2 = __builtin_amdgcn_mfma_f32_16x16x32_bf16(Bk0, a0[2], C2, 0, 0, 0);
                C3 = __builtin_amdgcn_mfma_f32_16x16x32_bf16(Bk0, a0[3], C3, 0, 0, 0);
                C0 = __builtin_amdgcn_mfma_f32_16x16x32_bf16(Bk1, aPE1, C0, 0, 0, 0);
                C1 = __builtin_amdgcn_mfma_f32_16x16x32_bf16(Bk1, aPE1, C1, 0, 0, 0);
                C2 = __builtin_amdgcn_mfma_f32_16x16x32_bf16(Bk1, aPE1, C2, 0, 0, 0);
                C3 = __builtin_amdgcn_mfma_f32_16x16x32_bf16(Bk1, aPE1, C3, 0, 0, 0);
                C0 = __builtin_amdgcn_mfma_f32_16x16x32_bf16(Bk2, aPE2, C0, 0, 0, 0);
                C1 = __builtin_amdgcn_mfma_f32_16x16x32_bf16(Bk2, aPE2, C1, 0, 0, 0);
                C2 = __builtin_amdgcn_mfma_f32_16x16x32_bf16(Bk2, aPE2, C2, 0, 0, 0);
                C3 = __builtin_amdgcn_mfma_f32_16x16x32_bf16(Bk2, aPE2, C3, 0, 0, 0);

                // relu -> bf16 -> H stripe: sample=16mb+c, local k = 16h + 4g + q
                f32x4 Cm[4] = {C0, C1, C2, C3};
                #pragma unroll
                for (int mb = 0; mb < 4; ++mb) {
                    uint2 w;
                    w.x = pk2(fmaxf(Cm[mb][0], 0.f), fmaxf(Cm[mb][1], 0.f));
                    w.y = pk2(fmaxf(Cm[mb][2], 0.f), fmaxf(Cm[mb][3], 0.f));
                    *reinterpret_cast<uint2*>(&hb[(16 * mb + c) * HSTRIDE + 16 * h + 4 * g]) = w;
                }
            }
            // Layer-2 MFMA over this 32-neuron K-step (compiler inserts lgkmcnt).
            #pragma unroll
            for (int t = 0; t < 4; ++t) {
                s16x8 Bf = *reinterpret_cast<const s16x8*>(&hb[(16 * t + c) * HSTRIDE + 8 * g]);
                D[t] = __builtin_amdgcn_mfma_f32_16x16x32_bf16(w2f[ks], Bf, D[t], 0, 0, 0);
            }
        }

        // Distribute preact: rows 0-3 live on g==0 lanes (row = 4g + q).
        if (g == 0) {
            #pragma unroll
            for (int t = 0; t < 4; ++t)
                *reinterpret_cast<f32x4*>(&ppre[wid][16 * t + c][0]) = D[t];
        }
        f32x4 pre = *reinterpret_cast<const f32x4*>(&ppre[wid][lane][0]);
        pre += b2v;

        float p0 = pre[0], p1 = pre[1], p2 = pre[2], p3 = pre[3];

        float density = fmaxf(p0, 0.0f);
        float dist = (intrs[(size_t)b * (N + 1) + n + 1] - intrs[(size_t)b * (N + 1) + n]) * nrm;
        float alpha = act ? (1.0f - expf(-density * dist)) : 0.0f;

        float fct = 1.0f - alpha + 1e-10f;
        float scan = fct;
        #pragma unroll
        for (int d = 1; d < 64; d <<= 1) {
            float o = __shfl_up(scan, d, 64);
            if (lane >= d) scan *= o;
        }
        float tot  = __shfl(scan, 63, 64);
        float excl = __shfl_up(scan, 1, 64);
        if (lane == 0) excl = 1.0f;

        float cum  = T * excl;
        float absl = alpha * cum;
        float sR = 1.0f / (1.0f + expf(-p1));
        float sG = 1.0f / (1.0f + expf(-p2));
        float sB = 1.0f / (1.0f + expf(-p3));
        aR = fmaf(absl, sR, aR);
        aG = fmaf(absl, sG, aG);
        aB = fmaf(absl, sB, aB);
        aA += absl;
        T *= tot;

        if (act) out_alpha[(size_t)b * N + n] = alpha;
    }

    #pragma unroll
    for (int d = 32; d > 0; d >>= 1) {
        aR += __shfl_down(aR, d, 64);
        aG += __shfl_down(aG, d, 64);
        aB += __shfl_down(aB, d, 64);
        aA += __shfl_down(aA, d, 64);
    }
    if (lane == 0) {
        out_comp[b * 3 + 0] = aR + (1.0f - aA);
        out_comp[b * 3 + 1] = aG + (1.0f - aA);
        out_comp[b * 3 + 2] = aB + (1.0f - aA);
    }
}

extern "C" void kernel_launch(void* const* d_in, const int* in_sizes, int n_in,
                              void* d_out, int out_size, void* d_ws, size_t ws_size,
                              hipStream_t stream) {
    const float* rays_d = (const float*)d_in[0];
    const float* intrs  = (const float*)d_in[1];
    const void*  maskp  = d_in[2];
    const float* data   = (const float*)d_in[3];
    const float* W1     = (const float*)d_in[4];
    const float* b1     = (const float*)d_in[5];
    const float* W2     = (const float*)d_in[6];
    const float* b2     = (const float*)d_in[7];
    float* out = (float*)d_out;

    int B = in_sizes[0] / 3;            // 8192
    int N = in_sizes[2] / B;            // 256
    int P = in_sizes[3] / DATA_DIM;     // packed sample count

    int* wsI    = (int*)d_ws;
    int* cnt    = wsI + 64;
    int* roff   = wsI + 64 + B;
    short* W1bf = (short*)(wsI + 64 + 2 * B);

    k_zero<<<1, 1, 0, stream>>>(wsI);
    int nwords = (B * N) / 4;
    k_count_bytes<<<256, 256, 0, stream>>>((const unsigned int*)maskp, nwords, wsI);
    k_set_flag<<<1, 1, 0, stream>>>(wsI, P);
    k_ray_count<<<B, 64, 0, stream>>>(maskp, wsI + 1, cnt, N);
    k_scan<<<1, 1024, 0, stream>>>(cnt, roff, B);
    k_prep<<<(WIDTH * KPAD + 255) / 256, 256, 0, stream>>>(W1, b1, W1bf);
    k_render<<<B / 4, 256, 0, stream>>>(rays_d, intrs, maskp, data, W1bf, W2, b2,
                                        wsI + 1, roff, out, B, N, P);
}

// Round 6
// 120.230 us; speedup vs baseline: 2.7097x; 1.3380x over previous
//
#include <hip/hip_runtime.h>
#include <hip/hip_bf16.h>
#include <math.h>

#define FREQS 9
#define DATA_DIM 28
#define WIDTH 128
#define IN_DIM 82
#define KPAD 96
#define HSTRIDE 40   // shorts per sample row in H stripe (80 B) -> 2-way conflicts (free)

typedef float f32x4 __attribute__((ext_vector_type(4)));
typedef short s16x8 __attribute__((ext_vector_type(8)));

__device__ __forceinline__ short f2bf(float f) {
    unsigned u = __builtin_bit_cast(unsigned, f);
    u += 0x7fffu + ((u >> 16) & 1u);
    return (short)(u >> 16);
}

__device__ __forceinline__ unsigned pk2(float a, float b) {
    unsigned lo = (unsigned)(unsigned short)f2bf(a);
    unsigned hi = (unsigned)(unsigned short)f2bf(b);
    return lo | (hi << 16);
}

// ws: [0] nz counter, [1] mask-width flag, [64..64+B) counts, [64+B..64+2B) offsets,
// then W1bf (128*96 bf16, b1 folded at k=82)

__global__ void k_zero(int* ws) { ws[0] = 0; }

__global__ void k_count_bytes(const unsigned int* __restrict__ mw, int nwords, int* ws) {
    int tid = blockIdx.x * blockDim.x + threadIdx.x;
    int stride = gridDim.x * blockDim.x;
    int c = 0;
    for (int i = tid; i < nwords; i += stride) {
        unsigned int w = mw[i];
        c += ((w & 0xffu) != 0) + (((w >> 8) & 0xffu) != 0) +
             (((w >> 16) & 0xffu) != 0) + ((w >> 24) != 0);
    }
    __shared__ int red[256];
    red[threadIdx.x] = c;
    __syncthreads();
    for (int off = 128; off > 0; off >>= 1) {
        if (threadIdx.x < off) red[threadIdx.x] += red[threadIdx.x + off];
        __syncthreads();
    }
    if (threadIdx.x == 0) atomicAdd(&ws[0], red[0]);
}

__global__ void k_set_flag(int* ws, int P) { ws[1] = (ws[0] == P) ? 1 : 0; }

__global__ void k_ray_count(const void* __restrict__ maskp, const int* __restrict__ wsflag,
                            int* __restrict__ cnt, int N) {
    int b = blockIdx.x;
    int lane = threadIdx.x;
    int fl = wsflag[0];
    const unsigned char* m8 = (const unsigned char*)maskp;
    const int* m32 = (const int*)maskp;
    int base = 0;
    for (int t = 0; t < N / 64; ++t) {
        int n = t * 64 + lane;
        int mv = fl ? (int)m8[(size_t)b * N + n] : m32[(size_t)b * N + n];
        unsigned long long bal = __ballot(mv != 0);
        base += __popcll(bal);
    }
    if (lane == 0) cnt[b] = base;
}

__global__ void k_scan(const int* __restrict__ cnt, int* __restrict__ roff, int Bn) {
    __shared__ int sums[1024];
    int tid = threadIdx.x;
    int per = Bn / 1024;
    int loc[8];
    int s = 0;
    for (int i = 0; i < per; ++i) { loc[i] = s; s += cnt[tid * per + i]; }
    sums[tid] = s;
    __syncthreads();
    for (int off = 1; off < 1024; off <<= 1) {
        int t = sums[tid];
        int v = (tid >= off) ? sums[tid - off] : 0;
        __syncthreads();
        sums[tid] = t + v;
        __syncthreads();
    }
    int excl = sums[tid] - s;
    for (int i = 0; i < per; ++i) roff[tid * per + i] = excl + loc[i];
}

__global__ void k_prep(const float* __restrict__ W1, const float* __restrict__ b1,
                       short* __restrict__ W1bf) {
    int tid = blockIdx.x * blockDim.x + threadIdx.x;
    if (tid < WIDTH * KPAD) {
        int n = tid / KPAD, k = tid - n * KPAD;
        float v = (k < IN_DIM) ? W1[n * IN_DIM + k] : ((k == IN_DIM) ? b1[n] : 0.0f);
        W1bf[tid] = f2bf(v);
    }
}

// 256 threads = 4 waves = 4 rays per block; waves fully independent (no barriers).
// launch_bounds(256,2): 256-reg cap -> no spill (R2/R5 lesson: the 170-reg cap of
// (256,3) forces an 84/84 arch/acc split + ~100MB scratch traffic).
__global__ __launch_bounds__(256, 2) void k_render(
    const float* __restrict__ rays_d, const float* __restrict__ intrs,
    const void* __restrict__ maskp, const float* __restrict__ data,
    const short* __restrict__ W1bf, const float* __restrict__ W2,
    const float* __restrict__ b2,
    const int* __restrict__ wsflag, const int* __restrict__ roff,
    float* __restrict__ out, int Bn, int N, int P)
{
    int wid = threadIdx.x >> 6;
    int lane = threadIdx.x & 63;
    int b = blockIdx.x * 4 + wid;
    int g = lane >> 4, c = lane & 15;

    float* out_comp = out;
    float* out_alpha = out + (size_t)Bn * 3;

    __shared__ int nlist[4][256];
    __shared__ __align__(16) short hbuf[4][64 * HSTRIDE];   // 20 KB
    __shared__ __align__(16) float ppre[4][64][4];          // 4 KB

    int fl = wsflag[0];
    const unsigned char* m8 = (const unsigned char*)maskp;
    const int* m32 = (const int*)maskp;

    // Phase 1: per-wave masked-n list; zero alpha for unmasked.
    int base = 0;
    for (int t = 0; t < N / 64; ++t) {
        int n = t * 64 + lane;
        int mv = fl ? (int)m8[(size_t)b * N + n] : m32[(size_t)b * N + n];
        bool m = (mv != 0);
        unsigned long long bal = __ballot(m);
        int rank = __popcll(bal & ((1ull << lane) - 1ull));
        if (m) nlist[wid][base + rank] = n;
        else   out_alpha[(size_t)b * N + n] = 0.0f;
        base += __popcll(bal);
    }
    int count = base;
    int poff = roff[b];

    float dx = rays_d[b * 3 + 0], dy = rays_d[b * 3 + 1], dz = rays_d[b * 3 + 2];
    float nrm = sqrtf(dx * dx + dy * dy + dz * dz);

    // PE lane-parallel: pe[f*6+t], t<3: sin(d[t]*2^f), else cos.
    int idx = (lane < 54) ? lane : 0;
    int fb = idx / 6, t5 = idx - fb * 6;
    int ax = (t5 < 3) ? t5 : (t5 - 3);
    float dv = (ax == 0) ? dx : ((ax == 1) ? dy : dz);
    float ang = dv * (float)(1 << fb);
    float pev = (t5 < 3) ? sinf(ang) : cosf(ang);

    // X fragments for K-steps 1,2 (per-ray constant). k=82 -> 1.0 (bias column).
    s16x8 aPE1, aPE2;
    #pragma unroll
    for (int j = 0; j < 8; ++j) {
        int i1 = 4 + 8 * g + j;
        aPE1[j] = f2bf(__shfl(pev, i1, 64));
        int i2 = 36 + 8 * g + j;
        float v2 = __shfl(pev, (i2 < 54) ? i2 : 0, 64);
        float vv = (i2 < 54) ? v2 : ((i2 == 54) ? 1.0f : 0.0f);
        aPE2[j] = f2bf(vv);
    }
    unsigned peTx = pk2(__shfl(pev, 0, 64), __shfl(pev, 1, 64));   // k=28,29
    unsigned peTy = pk2(__shfl(pev, 2, 64), __shfl(pev, 3, 64));   // k=30,31

    // W2 A-fragments (per-lane constant): A[row=c][k=32ks+8g+j], rows>=4 zero.
    s16x8 w2f[4];
    #pragma unroll
    for (int ks = 0; ks < 4; ++ks) {
        if (c < 4) {
            const float* wp = W2 + c * WIDTH + 32 * ks + 8 * g;
            f32x4 u = *reinterpret_cast<const f32x4*>(wp);
            f32x4 v = *reinterpret_cast<const f32x4*>(wp + 4);
            #pragma unroll
            for (int j = 0; j < 4; ++j) {
                w2f[ks][j] = f2bf(u[j]);
                w2f[ks][4 + j] = f2bf(v[j]);
            }
        } else {
            #pragma unroll
            for (int j = 0; j < 8; ++j) w2f[ks][j] = 0;
        }
    }

    f32x4 b2v = *reinterpret_cast<const f32x4*>(b2);
    const s16x8* W1v = reinterpret_cast<const s16x8*>(W1bf);
    short* hb = &hbuf[wid][0];

    float T = 1.0f;
    float aR = 0.f, aG = 0.f, aB = 0.f, aA = 0.f;

    for (int r0 = 0; r0 < count; r0 += 64) {
        int r = r0 + lane;
        bool act = (r < count);
        int n = act ? nlist[wid][r] : 0;

        // X B-fragments, K-step 0: data cols (g=3: 24..27 + pe tail)
        s16x8 a0[4];
        #pragma unroll
        for (int mb = 0; mb < 4; ++mb) {
            int srow = poff + r0 + 16 * mb + c;
            srow = (srow < P) ? srow : (P - 1);
            const float* dr = data + (size_t)srow * DATA_DIM;
            f32x4 lo = *reinterpret_cast<const f32x4*>(dr + 8 * g);
            unsigned u0 = pk2(lo[0], lo[1]);
            unsigned u1 = pk2(lo[2], lo[3]);
            unsigned u2, u3;
            if (g < 3) {
                f32x4 hi = *reinterpret_cast<const f32x4*>(dr + 8 * g + 4);
                u2 = pk2(hi[0], hi[1]);
                u3 = pk2(hi[2], hi[3]);
            } else {
                u2 = peTx; u3 = peTy;
            }
            uint4 uu; uu.x = u0; uu.y = u1; uu.z = u2; uu.w = u3;
            a0[mb] = __builtin_bit_cast(s16x8, uu);
        }

        f32x4 D[4];
        #pragma unroll
        for (int t = 0; t < 4; ++t) D[t] = (f32x4){0.f, 0.f, 0.f, 0.f};

        #pragma unroll
        for (int ks = 0; ks < 4; ++ks) {
            #pragma unroll
            for (int h = 0; h < 2; ++h) {
                int nt = 2 * ks + h;
                int nrow = 16 * nt + c;
                s16x8 Bk0 = W1v[nrow * 12 + g];
                s16x8 Bk1 = W1v[nrow * 12 + 4 + g];
                s16x8 Bk2 = W1v[nrow * 12 + 8 + g];

                f32x4 C0 = {0.f,0.f,0.f,0.f}, C1 = C0, C2 = C0, C3 = C0;
                C0 = __builtin_amdgcn_mfma_f32_16x16x32_bf16(Bk0, a0[0], C0, 0, 0, 0);
                C1 = __builtin_amdgcn_mfma_f32_16x16x32_bf16(Bk0, a0[1], C1, 0, 0, 0);
                C2 = __builtin_amdgcn_mfma_f32_16x16x32_bf16(Bk0, a0[2], C2, 0, 0, 0);
                C3 = __builtin_amdgcn_mfma_f32_16x16x32_bf16(Bk0, a0[3], C3, 0, 0, 0);
                C0 = __builtin_amdgcn_mfma_f32_16x16x32_bf16(Bk1, aPE1, C0, 0, 0, 0);
                C1 = __builtin_amdgcn_mfma_f32_16x16x32_bf16(Bk1, aPE1, C1, 0, 0, 0);
                C2 = __builtin_amdgcn_mfma_f32_16x16x32_bf16(Bk1, aPE1, C2, 0, 0, 0);
                C3 = __builtin_amdgcn_mfma_f32_16x16x32_bf16(Bk1, aPE1, C3, 0, 0, 0);
                C0 = __builtin_amdgcn_mfma_f32_16x16x32_bf16(Bk2, aPE2, C0, 0, 0, 0);
                C1 = __builtin_amdgcn_mfma_f32_16x16x32_bf16(Bk2, aPE2, C1, 0, 0, 0);
                C2 = __builtin_amdgcn_mfma_f32_16x16x32_bf16(Bk2, aPE2, C2, 0, 0, 0);
                C3 = __builtin_amdgcn_mfma_f32_16x16x32_bf16(Bk2, aPE2, C3, 0, 0, 0);

                // relu -> bf16 -> H stripe: sample=16mb+c, local k = 16h + 4g + q
                f32x4 Cm[4] = {C0, C1, C2, C3};
                #pragma unroll
                for (int mb = 0; mb < 4; ++mb) {
                    uint2 w;
                    w.x = pk2(fmaxf(Cm[mb][0], 0.f), fmaxf(Cm[mb][1], 0.f));
                    w.y = pk2(fmaxf(Cm[mb][2], 0.f), fmaxf(Cm[mb][3], 0.f));
                    *reinterpret_cast<uint2*>(&hb[(16 * mb + c) * HSTRIDE + 16 * h + 4 * g]) = w;
                }
            }
            // Layer-2 MFMA over this 32-neuron K-step (compiler inserts lgkmcnt).
            #pragma unroll
            for (int t = 0; t < 4; ++t) {
                s16x8 Bf = *reinterpret_cast<const s16x8*>(&hb[(16 * t + c) * HSTRIDE + 8 * g]);
                D[t] = __builtin_amdgcn_mfma_f32_16x16x32_bf16(w2f[ks], Bf, D[t], 0, 0, 0);
            }
        }

        // Distribute preact: rows 0-3 live on g==0 lanes (row = 4g + q).
        if (g == 0) {
            #pragma unroll
            for (int t = 0; t < 4; ++t)
                *reinterpret_cast<f32x4*>(&ppre[wid][16 * t + c][0]) = D[t];
        }
        f32x4 pre = *reinterpret_cast<const f32x4*>(&ppre[wid][lane][0]);
        pre += b2v;

        float p0 = pre[0], p1 = pre[1], p2 = pre[2], p3 = pre[3];

        float density = fmaxf(p0, 0.0f);
        float dist = (intrs[(size_t)b * (N + 1) + n + 1] - intrs[(size_t)b * (N + 1) + n]) * nrm;
        float alpha = act ? (1.0f - expf(-density * dist)) : 0.0f;

        float fct = 1.0f - alpha + 1e-10f;
        float scan = fct;
        #pragma unroll
        for (int d = 1; d < 64; d <<= 1) {
            float o = __shfl_up(scan, d, 64);
            if (lane >= d) scan *= o;
        }
        float tot  = __shfl(scan, 63, 64);
        float excl = __shfl_up(scan, 1, 64);
        if (lane == 0) excl = 1.0f;

        float cum  = T * excl;
        float absl = alpha * cum;
        float sR = 1.0f / (1.0f + expf(-p1));
        float sG = 1.0f / (1.0f + expf(-p2));
        float sB = 1.0f / (1.0f + expf(-p3));
        aR = fmaf(absl, sR, aR);
        aG = fmaf(absl, sG, aG);
        aB = fmaf(absl, sB, aB);
        aA += absl;
        T *= tot;

        if (act) out_alpha[(size_t)b * N + n] = alpha;
    }

    #pragma unroll
    for (int d = 32; d > 0; d >>= 1) {
        aR += __shfl_down(aR, d, 64);
        aG += __shfl_down(aG, d, 64);
        aB += __shfl_down(aB, d, 64);
        aA += __shfl_down(aA, d, 64);
    }
    if (lane == 0) {
        out_comp[b * 3 + 0] = aR + (1.0f - aA);
        out_comp[b * 3 + 1] = aG + (1.0f - aA);
        out_comp[b * 3 + 2] = aB + (1.0f - aA);
    }
}

extern "C" void kernel_launch(void* const* d_in, const int* in_sizes, int n_in,
                              void* d_out, int out_size, void* d_ws, size_t ws_size,
                              hipStream_t stream) {
    const float* rays_d = (const float*)d_in[0];
    const float* intrs  = (const float*)d_in[1];
    const void*  maskp  = d_in[2];
    const float* data   = (const float*)d_in[3];
    const float* W1     = (const float*)d_in[4];
    const float* b1     = (const float*)d_in[5];
    const float* W2     = (const float*)d_in[6];
    const float* b2     = (const float*)d_in[7];
    float* out = (float*)d_out;

    int B = in_sizes[0] / 3;            // 8192
    int N = in_sizes[2] / B;            // 256
    int P = in_sizes[3] / DATA_DIM;     // packed sample count

    int* wsI    = (int*)d_ws;
    int* cnt    = wsI + 64;
    int* roff   = wsI + 64 + B;
    short* W1bf = (short*)(wsI + 64 + 2 * B);

    k_zero<<<1, 1, 0, stream>>>(wsI);
    int nwords = (B * N) / 4;
    k_count_bytes<<<256, 256, 0, stream>>>((const unsigned int*)maskp, nwords, wsI);
    k_set_flag<<<1, 1, 0, stream>>>(wsI, P);
    k_ray_count<<<B, 64, 0, stream>>>(maskp, wsI + 1, cnt, N);
    k_scan<<<1, 1024, 0, stream>>>(cnt, roff, B);
    k_prep<<<(WIDTH * KPAD + 255) / 256, 256, 0, stream>>>(W1, b1, W1bf);
    k_render<<<B / 4, 256, 0, stream>>>(rays_d, intrs, maskp, data, W1bf, W2, b2,
                                        wsI + 1, roff, out, B, N, P);
}